// Round 6
// baseline (657.055 us; speedup 1.0000x reference)
//
#include <hip/hip_runtime.h>
#include <cstdint>
#include <cstddef>

#define T_STEPS 64
#define BATCH 512
#define IN_F 784
#define KP 800          // padded K for W arrays (25*32)
#define HID 2048
#define OUT_F 10

#define DEC_V 0.9f
#define DEC_I 0.8f
#define DT_V 0.1f
#define V_TH 0.5f

typedef __attribute__((ext_vector_type(8))) _Float16 f16x8;
typedef __attribute__((ext_vector_type(4))) _Float16 f16x4;
typedef __attribute__((ext_vector_type(2))) __fp16 fp16v2;   // cvt_pkrtz return type
typedef __attribute__((ext_vector_type(4))) float f32x4;

__device__ __forceinline__ void load_lds16h(const _Float16* g, _Float16* l) {
  __builtin_amdgcn_global_load_lds(
      (const __attribute__((address_space(1))) void*)g,
      (__attribute__((address_space(3))) void*)l, 16, 0, 0);
}
__device__ __forceinline__ void load_lds16f(const float* g, float* l) {
  __builtin_amdgcn_global_load_lds(
      (const __attribute__((address_space(1))) void*)g,
      (__attribute__((address_space(3))) void*)l, 16, 0, 0);
}

// ---------------------------------------------------------------------------
// One-time: split w1 fp32 rows into f16 hi/lo, K padded 784->800 with zeros.
// ---------------------------------------------------------------------------
__global__ __launch_bounds__(256)
void split_w(const float* __restrict__ src, _Float16* __restrict__ hi,
             _Float16* __restrict__ lo) {
  const int row = blockIdx.x * 2 + (threadIdx.x >> 7);
  const int ln = threadIdx.x & 127;
  const float4* s = (const float4*)(src + (size_t)row * IN_F);
#pragma unroll
  for (int it = 0; it < 2; ++it) {
    const int q = ln + it * 128;               // quad index, 200 per row
    if (q >= 200) break;
    float4 v = (q < 196) ? s[q] : make_float4(0.f, 0.f, 0.f, 0.f);
    f16x4 h, l;
    h.x = (_Float16)v.x; l.x = (_Float16)(v.x - (float)h.x);
    h.y = (_Float16)v.y; l.y = (_Float16)(v.y - (float)h.y);
    h.z = (_Float16)v.z; l.z = (_Float16)(v.z - (float)h.z);
    h.w = (_Float16)v.w; l.w = (_Float16)(v.w - (float)h.w);
    *(f16x4*)&hi[(size_t)row * KP + q * 4] = h;
    *(f16x4*)&lo[(size_t)row * KP + q * 4] = l;
  }
}

// ---------------------------------------------------------------------------
// MFMA GEMM, fragment-order LDS (conflict-free b128 reads at base+lane*16).
// C[m,n] = sum_k A[m,k]*W[n,k]; A raw fp32 [M,784] split to f16 hi/lo
// in-register (trunc-13-bit hi + RTZ lo, err ~2^-20); W pre-split f16 [KP].
// 128x128 tile, 4 waves x (4x4 of 16x16x32), 3 MFMA products per tile.
// LDS slot for tile t, lane l holds row (l&15), k-quad (l>>4) — exactly the
// MFMA fragment, so frag reads are the m134 conflict-free b128 pattern.
// ---------------------------------------------------------------------------
__global__ __launch_bounds__(256, 2)
void gemm_fc1(const float* __restrict__ A, const _Float16* __restrict__ Wh,
              const _Float16* __restrict__ Wl, float* __restrict__ C) {
  __shared__ float    sA [8 * 512];   // 16 KB: [tile][half][lane*4 f32]
  __shared__ _Float16 sWh[8 * 512];   //  8 KB: [tile][lane*8 halves]
  __shared__ _Float16 sWl[8 * 512];   //  8 KB

  const int tid = threadIdx.x;
  const int lane = tid & 63;
  const int wv = tid >> 6;
  const int bn = blockIdx.x * 128;
  const int bm = blockIdx.y * 128;

  const int srow = lane & 15;         // row within staged tile
  const int sq = lane >> 4;           // k-quad 0..3

  const int t0i = wv * 2, t1i = wv * 2 + 1;   // tiles staged by this wave
  const float*    a0 = A  + (size_t)(bm + t0i * 16 + srow) * IN_F + sq * 8;
  const float*    a1 = A  + (size_t)(bm + t1i * 16 + srow) * IN_F + sq * 8;
  const _Float16* h0 = Wh + (size_t)(bn + t0i * 16 + srow) * KP + sq * 8;
  const _Float16* h1 = Wh + (size_t)(bn + t1i * 16 + srow) * KP + sq * 8;
  const _Float16* l0 = Wl + (size_t)(bn + t0i * 16 + srow) * KP + sq * 8;
  const _Float16* l1 = Wl + (size_t)(bn + t1i * 16 + srow) * KP + sq * 8;

  // compute decomposition
  const int wr = (wv >> 1) * 64;
  const int wc = (wv & 1) * 64;
  const int col = lane & 15;
  const int quad = lane >> 4;
  const int wrT = wr >> 4, wcT = wc >> 4;

  f32x4 acc[4][4] = {};

  for (int k0 = 0; k0 < KP; k0 += 32) {
    __syncthreads();
    const bool tail = (k0 + 32 > IN_F);       // only k0 == 768
    if (!tail) {
      load_lds16f(a0 + k0,     sA + t0i * 512);
      load_lds16f(a0 + k0 + 4, sA + t0i * 512 + 256);
      load_lds16f(a1 + k0,     sA + t1i * 512);
      load_lds16f(a1 + k0 + 4, sA + t1i * 512 + 256);
    } else {
      if (sq >= 2) {                          // k >= 784: zero these slots
        const float4 z4 = make_float4(0.f, 0.f, 0.f, 0.f);
        *(float4*)&sA[t0i * 512 +       lane * 4] = z4;
        *(float4*)&sA[t0i * 512 + 256 + lane * 4] = z4;
        *(float4*)&sA[t1i * 512 +       lane * 4] = z4;
        *(float4*)&sA[t1i * 512 + 256 + lane * 4] = z4;
      } else {
        load_lds16f(a0 + k0,     sA + t0i * 512);
        load_lds16f(a0 + k0 + 4, sA + t0i * 512 + 256);
        load_lds16f(a1 + k0,     sA + t1i * 512);
        load_lds16f(a1 + k0 + 4, sA + t1i * 512 + 256);
      }
    }
    load_lds16h(h0 + k0, sWh + t0i * 512);
    load_lds16h(l0 + k0, sWl + t0i * 512);
    load_lds16h(h1 + k0, sWh + t1i * 512);
    load_lds16h(l1 + k0, sWl + t1i * 512);
    __syncthreads();

    f16x8 fah[4], fal[4], fwh[4], fwl[4];
#pragma unroll
    for (int i = 0; i < 4; ++i) {
      fwh[i] = *(const f16x8*)&sWh[(wcT + i) * 512 + lane * 8];
      fwl[i] = *(const f16x8*)&sWl[(wcT + i) * 512 + lane * 8];
      const float4 p0 = *(const float4*)&sA[(wrT + i) * 512 +       lane * 4];
      const float4 p1 = *(const float4*)&sA[(wrT + i) * 512 + 256 + lane * 4];
      // hi = truncate mantissa to f16 precision (exact under cvt_pkrtz)
      const float hx0 = __uint_as_float(__float_as_uint(p0.x) & 0xffffe000u);
      const float hy0 = __uint_as_float(__float_as_uint(p0.y) & 0xffffe000u);
      const float hz0 = __uint_as_float(__float_as_uint(p0.z) & 0xffffe000u);
      const float hw0 = __uint_as_float(__float_as_uint(p0.w) & 0xffffe000u);
      const float hx1 = __uint_as_float(__float_as_uint(p1.x) & 0xffffe000u);
      const float hy1 = __uint_as_float(__float_as_uint(p1.y) & 0xffffe000u);
      const float hz1 = __uint_as_float(__float_as_uint(p1.z) & 0xffffe000u);
      const float hw1 = __uint_as_float(__float_as_uint(p1.w) & 0xffffe000u);
      union { f16x8 v; fp16v2 h[4]; } uh, ul;
      uh.h[0] = __builtin_amdgcn_cvt_pkrtz(hx0, hy0);
      uh.h[1] = __builtin_amdgcn_cvt_pkrtz(hz0, hw0);
      uh.h[2] = __builtin_amdgcn_cvt_pkrtz(hx1, hy1);
      uh.h[3] = __builtin_amdgcn_cvt_pkrtz(hz1, hw1);
      ul.h[0] = __builtin_amdgcn_cvt_pkrtz(p0.x - hx0, p0.y - hy0);
      ul.h[1] = __builtin_amdgcn_cvt_pkrtz(p0.z - hz0, p0.w - hw0);
      ul.h[2] = __builtin_amdgcn_cvt_pkrtz(p1.x - hx1, p1.y - hy1);
      ul.h[3] = __builtin_amdgcn_cvt_pkrtz(p1.z - hz1, p1.w - hw1);
      fah[i] = uh.v;
      fal[i] = ul.v;
    }
#pragma unroll
    for (int mi = 0; mi < 4; ++mi)
#pragma unroll
      for (int ni = 0; ni < 4; ++ni) {
        acc[mi][ni] = __builtin_amdgcn_mfma_f32_16x16x32_f16(fah[mi], fwh[ni], acc[mi][ni], 0, 0, 0);
        acc[mi][ni] = __builtin_amdgcn_mfma_f32_16x16x32_f16(fah[mi], fwl[ni], acc[mi][ni], 0, 0, 0);
        acc[mi][ni] = __builtin_amdgcn_mfma_f32_16x16x32_f16(fal[mi], fwh[ni], acc[mi][ni], 0, 0, 0);
      }
  }

  // C/D layout: col = lane&15, row = quad*4 + reg
#pragma unroll
  for (int mi = 0; mi < 4; ++mi)
#pragma unroll
    for (int ni = 0; ni < 4; ++ni)
#pragma unroll
      for (int r = 0; r < 4; ++r) {
        const int row = bm + wr + mi * 16 + quad * 4 + r;
        const int cg = bn + wc + ni * 16 + col;
        C[(size_t)row * HID + cg] = acc[mi][ni][r];
      }
}

// ---------------------------------------------------------------------------
// Fused LIF scan + output projection partials (unchanged from R4 — passed).
// ---------------------------------------------------------------------------
__global__ __launch_bounds__(256)
void lif_out(const float* __restrict__ cur, const float* __restrict__ wo,
             float* __restrict__ v1, float* __restrict__ i1,
             float* __restrict__ outP, int tc, int t0) {
  __shared__ _Float16 zL[T_STEPS][264];
  __shared__ _Float16 wT[16][264];

  const int tid = threadIdx.x;
  const int hc = blockIdx.x;
  const int b = blockIdx.y;
  const int hb = hc * 256;

  for (int i = tid; i < 16 * 256; i += 256) {
    const int n = i >> 8, k = i & 255;
    wT[n][k] = (n < OUT_F) ? (_Float16)wo[(size_t)n * HID + hb + k] : (_Float16)0.f;
  }

  const int sidx = b * HID + hb + tid;
  float v = v1[sidx];
  float ci = i1[sidx];
#pragma unroll 4
  for (int t = 0; t < tc; ++t) {
    const float c = cur[(size_t)t * (BATCH * HID) + sidx];
    const float vd = DEC_V * v + DT_V * ci;
    const float z = (vd > V_TH) ? 1.0f : 0.0f;
    v = (1.0f - z) * vd;
    ci = DEC_I * ci + c;
    zL[t][tid] = (_Float16)z;
  }
  v1[sidx] = v;
  i1[sidx] = ci;
  __syncthreads();

  const int wv = tid >> 6;
  const int lane = tid & 63;
  const int col = lane & 15;
  const int quad = lane >> 4;
  f32x4 acc = {};
  const _Float16* za = &zL[wv * 16 + col][0];
  const _Float16* wb = &wT[col][0];
#pragma unroll
  for (int ks = 0; ks < 8; ++ks) {
    f16x8 a = *(const f16x8*)(za + ks * 32 + quad * 8);
    f16x8 bb = *(const f16x8*)(wb + ks * 32 + quad * 8);
    acc = __builtin_amdgcn_mfma_f32_16x16x32_f16(a, bb, acc, 0, 0, 0);
  }
  if (col < OUT_F) {
#pragma unroll
    for (int r = 0; r < 4; ++r) {
      const int t = wv * 16 + quad * 4 + r;
      if (t < tc)
        outP[(((size_t)hc * T_STEPS + (t0 + t)) * BATCH + b) * OUT_F + col] = acc[r];
    }
  }
}

// ---------------------------------------------------------------------------
// LI readout: sum 8 chunk partials, scan, max. One thread per (b,o).
// ---------------------------------------------------------------------------
__global__ __launch_bounds__(256)
void li_scan(const float* __restrict__ outP, float* __restrict__ out) {
  const int idx = blockIdx.x * 256 + threadIdx.x;
  if (idx >= BATCH * OUT_F) return;
  float vo = 0.f, io = 0.f, vmax = 0.f;
  for (int t = 0; t < T_STEPS; ++t) {
    float oc = 0.f;
#pragma unroll
    for (int hc = 0; hc < 8; ++hc)
      oc += outP[((size_t)hc * T_STEPS + t) * (BATCH * OUT_F) + idx];
    const float von = DEC_V * vo + DT_V * io;
    io = DEC_I * io + oc;
    vo = von;
    vmax = fmaxf(vmax, von);
  }
  out[idx] = vmax;
}

__global__ void zero_state(float* __restrict__ p, int n) {
  int i = blockIdx.x * 256 + threadIdx.x;
  if (i < n) p[i] = 0.0f;
}

// ---------------------------------------------------------------------------
extern "C" void kernel_launch(void* const* d_in, const int* in_sizes, int n_in,
                              void* d_out, int out_size, void* d_ws, size_t ws_size,
                              hipStream_t stream) {
  const float* x  = (const float*)d_in[0];  // [T*B, 784]
  const float* w1 = (const float*)d_in[1];  // [2048, 784]
  const float* wo = (const float*)d_in[2];  // [10, 2048]
  float* out = (float*)d_out;               // [512, 10]

  const size_t BH = (size_t)BATCH * HID;

  // fixed: v1 | i1 | outP[8][T*B*10] | WhG | WlG ; chunked: cur[Tc][B][HID]
  float* v1 = (float*)d_ws;
  float* i1 = v1 + BH;
  float* outP = i1 + BH;
  _Float16* WhG = (_Float16*)(outP + (size_t)8 * T_STEPS * BATCH * OUT_F);
  _Float16* WlG = WhG + (size_t)HID * KP;
  float* cur = (float*)(WlG + (size_t)HID * KP);

  const size_t base_bytes = (size_t)((char*)cur - (char*)d_ws);
  const size_t per_step = BH * sizeof(float);
  int Tc = T_STEPS;
  while (Tc > 1 && base_bytes + (size_t)Tc * per_step > ws_size) Tc >>= 1;

  split_w<<<HID / 2, 256, 0, stream>>>(w1, WhG, WlG);
  zero_state<<<(int)((2 * BH + 255) / 256), 256, 0, stream>>>(v1, (int)(2 * BH));

  for (int t0 = 0; t0 < T_STEPS; t0 += Tc) {
    const int tc = (T_STEPS - t0 < Tc) ? (T_STEPS - t0) : Tc;
    const int nrows = tc * BATCH;
    dim3 grid(HID / 128, nrows / 128);
    gemm_fc1<<<grid, 256, 0, stream>>>(x + (size_t)t0 * BATCH * IN_F, WhG, WlG, cur);
    dim3 lgrid(HID / 256, BATCH);
    lif_out<<<lgrid, 256, 0, stream>>>(cur, wo, v1, i1, outP, tc, t0);
  }
  li_scan<<<(BATCH * OUT_F + 255) / 256, 256, 0, stream>>>(outP, out);
}

// Round 7
// 596.385 us; speedup vs baseline: 1.1017x; 1.1017x over previous
//
#include <hip/hip_runtime.h>
#include <cstdint>
#include <cstddef>

#define T_STEPS 64
#define BATCH 512
#define IN_F 784
#define NKT 25          // k-tiles of 32 (784 padded to 800)
#define HID 2048
#define OUT_F 10

#define DEC_V 0.9f
#define DEC_I 0.8f
#define DT_V 0.1f
#define V_TH 0.5f

typedef __attribute__((ext_vector_type(8))) _Float16 f16x8;
typedef __attribute__((ext_vector_type(4))) float f32x4;

__device__ __forceinline__ void load_lds16h(const _Float16* g, _Float16* l) {
  __builtin_amdgcn_global_load_lds(
      (const __attribute__((address_space(1))) void*)g,
      (__attribute__((address_space(3))) void*)l, 16, 0, 0);
}

// ---------------------------------------------------------------------------
// Split fp32 [nrows,784] into f16 hi/lo in FRAGMENT-TILE order:
// tile (mt = row/16, kt = k/32) is 512 halves; within tile, lane l holds
// row (l&15), k-slice (l>>4)*8..+8 — exactly the MFMA A/B fragment, so the
// gemm can DMA tiles with global_load_lds (dest = base + lane*16B).
// Block = one mt: coalesced row loads -> LDS -> fragment-order stores.
// ---------------------------------------------------------------------------
__global__ __launch_bounds__(256)
void split_frag(const float* __restrict__ src, _Float16* __restrict__ hiT,
                _Float16* __restrict__ loT) {
  __shared__ float xr[16][804];              // stride 804: 16B-aligned, 2-way banks
  const int mt = blockIdx.x;
  for (int i = threadIdx.x; i < 16 * IN_F; i += 256) {
    const int r = i / IN_F, c = i - r * IN_F;
    xr[r][c] = src[(size_t)(mt * 16 + r) * IN_F + c];
  }
  for (int i = threadIdx.x; i < 16 * 16; i += 256)
    xr[i >> 4][IN_F + (i & 15)] = 0.0f;      // pad k 784..799
  __syncthreads();

  const int l = threadIdx.x & 63;
  const int g = threadIdx.x >> 6;
  const int r = l & 15, q = l >> 4;
  for (int kt = g; kt < NKT; kt += 4) {
    const float* s = &xr[r][kt * 32 + q * 8];
    f16x8 h, lo;
#pragma unroll
    for (int j = 0; j < 8; ++j) {
      const float v = s[j];
      const _Float16 hh = (_Float16)v;       // RTN
      h[j] = hh;
      lo[j] = (_Float16)(v - (float)hh);
    }
    const size_t off = ((size_t)mt * NKT + kt) * 512 + l * 8;
    *(f16x8*)&hiT[off] = h;
    *(f16x8*)&loT[off] = lo;
  }
}

// ---------------------------------------------------------------------------
// MFMA GEMM: C[m,n] = sum_k A[m,k]*W[n,k] via 3x f16-split products.
// Inputs pre-split fragment-tile-ordered. Block tile 128(M) x 256(N), 4 waves,
// each wave 64x128 = 4x8 tiles of 16x16x32 (96 MFMA : 24 b128 frag reads).
// Staging: 12 global_load_lds DMAs per wave per ktile, conflict-free LDS.
// ---------------------------------------------------------------------------
__global__ __launch_bounds__(256, 2)
void gemm_fc1(const _Float16* __restrict__ AhT, const _Float16* __restrict__ AlT,
              const _Float16* __restrict__ WhT, const _Float16* __restrict__ WlT,
              float* __restrict__ C) {
  __shared__ _Float16 __attribute__((aligned(16))) sAh[8 * 512];
  __shared__ _Float16 __attribute__((aligned(16))) sAl[8 * 512];
  __shared__ _Float16 __attribute__((aligned(16))) sWh[16 * 512];
  __shared__ _Float16 __attribute__((aligned(16))) sWl[16 * 512];

  const int tid = threadIdx.x;
  const int lane = tid & 63;
  const int wv = tid >> 6;
  const int bmT = blockIdx.y * 8;            // A tile row base (m/16)
  const int bnT = blockIdx.x * 16;           // W tile row base (n/16)

  const int wrT = (wv >> 1) * 4;             // wave's A-tile offset (0/4)
  const int wcT = (wv & 1) * 8;              // wave's W-tile offset (0/8)
  const int col = lane & 15;
  const int quad = lane >> 4;

  f32x4 acc[4][8] = {};

  for (int kt = 0; kt < NKT; ++kt) {
    __syncthreads();
#pragma unroll
    for (int j = 0; j < 2; ++j) {            // A tiles wv*2, wv*2+1
      const int t = wv * 2 + j;
      const size_t go = ((size_t)(bmT + t) * NKT + kt) * 512 + lane * 8;
      load_lds16h(AhT + go, sAh + t * 512);
      load_lds16h(AlT + go, sAl + t * 512);
    }
#pragma unroll
    for (int j = 0; j < 4; ++j) {            // W tiles wv*4 .. wv*4+3
      const int t = wv * 4 + j;
      const size_t go = ((size_t)(bnT + t) * NKT + kt) * 512 + lane * 8;
      load_lds16h(WhT + go, sWh + t * 512);
      load_lds16h(WlT + go, sWl + t * 512);
    }
    __syncthreads();

    f16x8 fah[4], fal[4];
#pragma unroll
    for (int i = 0; i < 4; ++i) {
      fah[i] = *(const f16x8*)&sAh[(wrT + i) * 512 + lane * 8];
      fal[i] = *(const f16x8*)&sAl[(wrT + i) * 512 + lane * 8];
    }
#pragma unroll
    for (int ni = 0; ni < 8; ++ni) {
      const f16x8 fwh = *(const f16x8*)&sWh[(wcT + ni) * 512 + lane * 8];
      const f16x8 fwl = *(const f16x8*)&sWl[(wcT + ni) * 512 + lane * 8];
#pragma unroll
      for (int mi = 0; mi < 4; ++mi) {
        acc[mi][ni] = __builtin_amdgcn_mfma_f32_16x16x32_f16(fah[mi], fwh, acc[mi][ni], 0, 0, 0);
        acc[mi][ni] = __builtin_amdgcn_mfma_f32_16x16x32_f16(fah[mi], fwl, acc[mi][ni], 0, 0, 0);
        acc[mi][ni] = __builtin_amdgcn_mfma_f32_16x16x32_f16(fal[mi], fwh, acc[mi][ni], 0, 0, 0);
      }
    }
  }

  // C/D layout: col = lane&15, row = quad*4 + reg (R3/R4-verified)
  const int rowb = blockIdx.y * 128 + (wv >> 1) * 64;
  const int colb = blockIdx.x * 256 + (wv & 1) * 128;
#pragma unroll
  for (int mi = 0; mi < 4; ++mi)
#pragma unroll
    for (int ni = 0; ni < 8; ++ni)
#pragma unroll
      for (int r = 0; r < 4; ++r)
        C[(size_t)(rowb + mi * 16 + quad * 4 + r) * HID + colb + ni * 16 + col] =
            acc[mi][ni][r];
}

// ---------------------------------------------------------------------------
// Fused LIF scan + output projection partials (R4-verified, unchanged).
// ---------------------------------------------------------------------------
__global__ __launch_bounds__(256)
void lif_out(const float* __restrict__ cur, const float* __restrict__ wo,
             float* __restrict__ v1, float* __restrict__ i1,
             float* __restrict__ outP, int tc, int t0) {
  __shared__ _Float16 zL[T_STEPS][264];
  __shared__ _Float16 wT[16][264];

  const int tid = threadIdx.x;
  const int hc = blockIdx.x;
  const int b = blockIdx.y;
  const int hb = hc * 256;

  for (int i = tid; i < 16 * 256; i += 256) {
    const int n = i >> 8, k = i & 255;
    wT[n][k] = (n < OUT_F) ? (_Float16)wo[(size_t)n * HID + hb + k] : (_Float16)0.f;
  }

  const int sidx = b * HID + hb + tid;
  float v = v1[sidx];
  float ci = i1[sidx];
#pragma unroll 4
  for (int t = 0; t < tc; ++t) {
    const float c = cur[(size_t)t * (BATCH * HID) + sidx];
    const float vd = DEC_V * v + DT_V * ci;
    const float z = (vd > V_TH) ? 1.0f : 0.0f;
    v = (1.0f - z) * vd;
    ci = DEC_I * ci + c;
    zL[t][tid] = (_Float16)z;
  }
  v1[sidx] = v;
  i1[sidx] = ci;
  __syncthreads();

  const int wv = tid >> 6;
  const int lane = tid & 63;
  const int col = lane & 15;
  const int quad = lane >> 4;
  f32x4 acc = {};
  const _Float16* za = &zL[wv * 16 + col][0];
  const _Float16* wb = &wT[col][0];
#pragma unroll
  for (int ks = 0; ks < 8; ++ks) {
    f16x8 a = *(const f16x8*)(za + ks * 32 + quad * 8);
    f16x8 bb = *(const f16x8*)(wb + ks * 32 + quad * 8);
    acc = __builtin_amdgcn_mfma_f32_16x16x32_f16(a, bb, acc, 0, 0, 0);
  }
  if (col < OUT_F) {
#pragma unroll
    for (int r = 0; r < 4; ++r) {
      const int t = wv * 16 + quad * 4 + r;
      if (t < tc)
        outP[(((size_t)hc * T_STEPS + (t0 + t)) * BATCH + b) * OUT_F + col] = acc[r];
    }
  }
}

// ---------------------------------------------------------------------------
// LI readout: sum 8 chunk partials, scan, max. One thread per (b,o).
// ---------------------------------------------------------------------------
__global__ __launch_bounds__(256)
void li_scan(const float* __restrict__ outP, float* __restrict__ out) {
  const int idx = blockIdx.x * 256 + threadIdx.x;
  if (idx >= BATCH * OUT_F) return;
  float vo = 0.f, io = 0.f, vmax = 0.f;
  for (int t = 0; t < T_STEPS; ++t) {
    float oc = 0.f;
#pragma unroll
    for (int hc = 0; hc < 8; ++hc)
      oc += outP[((size_t)hc * T_STEPS + t) * (BATCH * OUT_F) + idx];
    const float von = DEC_V * vo + DT_V * io;
    io = DEC_I * io + oc;
    vo = von;
    vmax = fmaxf(vmax, von);
  }
  out[idx] = vmax;
}

__global__ void zero_state(float* __restrict__ p, int n) {
  int i = blockIdx.x * 256 + threadIdx.x;
  if (i < n) p[i] = 0.0f;
}

// ---------------------------------------------------------------------------
extern "C" void kernel_launch(void* const* d_in, const int* in_sizes, int n_in,
                              void* d_out, int out_size, void* d_ws, size_t ws_size,
                              hipStream_t stream) {
  const float* x  = (const float*)d_in[0];  // [T*B, 784]
  const float* w1 = (const float*)d_in[1];  // [2048, 784]
  const float* wo = (const float*)d_in[2];  // [10, 2048]
  float* out = (float*)d_out;               // [512, 10]

  const size_t BH = (size_t)BATCH * HID;
  const size_t WT_HALVES = (size_t)(HID / 16) * NKT * 512;   // per W array

  // fixed: v1 | i1 | outP[8][T*B*10] | WhT | WlT ; chunk: cur | AhT | AlT
  float* v1 = (float*)d_ws;
  float* i1 = v1 + BH;
  float* outP = i1 + BH;
  _Float16* WhT = (_Float16*)(outP + (size_t)8 * T_STEPS * BATCH * OUT_F);
  _Float16* WlT = WhT + WT_HALVES;
  char* chunk0 = (char*)(WlT + WT_HALVES);

  const size_t base_bytes = (size_t)(chunk0 - (char*)d_ws);
  // per step: cur f32 [512,2048] + AhT/AlT f16 [32 tiles][25][512]
  const size_t per_step = BH * 4 + (size_t)2 * 32 * NKT * 512 * 2;
  int Tc = T_STEPS;
  while (Tc > 1 && base_bytes + (size_t)Tc * per_step > ws_size) Tc >>= 1;

  float* cur = (float*)chunk0;
  _Float16* AhT = (_Float16*)(cur + (size_t)Tc * BH);
  _Float16* AlT = AhT + (size_t)Tc * 32 * NKT * 512;

  split_frag<<<HID / 16, 256, 0, stream>>>(w1, WhT, WlT);
  zero_state<<<(int)((2 * BH + 255) / 256), 256, 0, stream>>>(v1, (int)(2 * BH));

  for (int t0 = 0; t0 < T_STEPS; t0 += Tc) {
    const int tc = (T_STEPS - t0 < Tc) ? (T_STEPS - t0) : Tc;
    const int nrows = tc * BATCH;
    split_frag<<<nrows / 16, 256, 0, stream>>>(x + (size_t)t0 * BATCH * IN_F, AhT, AlT);
    dim3 grid(HID / 256, nrows / 128);
    gemm_fc1<<<grid, 256, 0, stream>>>(AhT, AlT, WhT, WlT, cur);
    dim3 lgrid(HID / 256, BATCH);
    lif_out<<<lgrid, 256, 0, stream>>>(cur, wo, v1, i1, outP, tc, t0);
  }
  li_scan<<<(BATCH * OUT_F + 255) / 256, 256, 0, stream>>>(outP, out);
}